// Round 10
// baseline (73.215 us; speedup 1.0000x reference)
//
#include <hip/hip_runtime.h>
#include <cmath>

// GRNN_3547642986522 — B=4096 filters, T=2048 steps.
// cov via constant-matrix LFT (Euler Riccati step == Kalman LFT step, O(dt^2));
// x affine given cov; f linear; t closed-form.
// Decomposition: lane owns one (b, s) chain; wave = 16 batches x 4 segments;
// block = 256 threads = 64 batches x 4 segments (all waves share sg).
// R10: NO LDS data staging — each lane's dy slice is 256B contiguous; direct
// vector loads give 16-deep MLP; direct 256B stores for dy_hat. Checkpoint
// matpow replaced by a block-shared 4-entry LUT (threads 0-3 compute ML^s,
// Mf^(32 s) once into LDS; lanes broadcast-read).
// k1: checkpoint + accumulate per-segment 2x2 transfer X / offset Q -> PQ.
// kfold: per batch, fold 64 segment maps; planes 4/5 := x at segment start.
// k2: checkpoint + x_start; replay 32 steps; store dy_hat; s==63 writes tails.
// ws: PQ planes [6][64][B] = 6.29 MiB.

#define NBATCH 4096
#define NT     2048
#define ROWF4  1024        // float4 per dy row
#define NSEG   64
#define LSEG   32
#define PLANE  (NSEG*NBATCH)
#define SEGF4  16          // f4 per segment slice (LSEG/2)

struct M16 { float m[16]; };

namespace gk {

constexpr float DT   = 0.001f;
constexpr float A00  = -0.15f;
constexpr float A01  = 6.283185f;
constexpr float A10  = -6.283185f;
constexpr float A11  = -0.15f;
constexpr float C0   = 1.6970562748477141f;
constexpr float DD   = 5.25f;

constexpr float P00c = 1.0f + DT*A00;
constexpr float P01c = DT*A01;
constexpr float P10c = DT*A10;
constexpr float P11c = 1.0f + DT*A11;
constexpr float DTC  = DT*C0;
constexpr float QQ   = DT*C0*C0;
constexpr float cVA  = 1.0f + 2.0f*DT*A00;
constexpr float cVB  = 2.0f*DT*A01;
constexpr float cVBn = 2.0f*DT*A10;
constexpr float cVD  = DT*DD;
constexpr float cCA  = 1.0f + DT*(A00+A11);
constexpr float cCB  = DT*A10;
constexpr float cCC  = DT*A01;
constexpr float YC   = C0*DT;

__device__ __forceinline__ void cov_step(float& vx, float& vp, float& cxp)
{
    float a1 = fmaf(-QQ, vx,  cVA);
    float b1 = fmaf(cVB, cxp, cVD);
    float a2 = fmaf(-QQ, cxp, cVBn);
    float b2 = fmaf(a2,  cxp, cVD);
    float a3 = fmaf(-QQ, vx,  cCA);
    float m  = cCC * vp;
    float c3 = fmaf(cCB, vx,  m);
    float nvx = fmaf(a1,  vx,  b1);
    float nvp = fmaf(cVA, vp,  b2);
    float ncx = fmaf(a3,  cxp, c3);
    vx = nvx; vp = nvp; cxp = ncx;
}

__device__ __forceinline__ void covf_step(
    float& vx, float& vp, float& cxp, float& f0, float& f1,
    float k00, float k01, float k10, float k11,
    float& xi0o, float& xi1o, float& nf0o)
{
    float xi0 = C0*vx, xi1 = C0*cxp;
    float nf0 = fmaf(DT, fmaf(k00, f0, k01*f1), f0);
    float nf1 = fmaf(DT, fmaf(k10, f0, k11*f1), f1);
    xi0o = xi0; xi1o = xi1; nf0o = nf0;
    cov_step(vx, vp, cxp);
    f0 = nf0; f1 = nf1;
}

__device__ __forceinline__ void mat4_mul(const float* A, const float* B, float* C)
{
    #pragma unroll
    for (int i = 0; i < 4; ++i)
        #pragma unroll
        for (int j = 0; j < 4; ++j) {
            float acc = A[i*4+0] * B[0*4+j];
            acc = fmaf(A[i*4+1], B[1*4+j], acc);
            acc = fmaf(A[i*4+2], B[2*4+j], acc);
            acc = fmaf(A[i*4+3], B[3*4+j], acc);
            C[i*4+j] = acc;
        }
}

// P -> (E P + F)(G P + H)^-1, P = [[vx,cxp],[cxp,vp]].
__device__ __forceinline__ void lft_apply(const float* m, float& vx, float& vp, float& cxp)
{
    float n00 = fmaf(m[0], vx,  fmaf(m[1], cxp, m[2]));
    float n01 = fmaf(m[0], cxp, fmaf(m[1], vp,  m[3]));
    float n10 = fmaf(m[4], vx,  fmaf(m[5], cxp, m[6]));
    float n11 = fmaf(m[4], cxp, fmaf(m[5], vp,  m[7]));
    float d00 = fmaf(m[8],  vx,  fmaf(m[9],  cxp, m[10]));
    float d01 = fmaf(m[8],  cxp, fmaf(m[9],  vp,  m[11]));
    float d10 = fmaf(m[12], vx,  fmaf(m[13], cxp, m[14]));
    float d11 = fmaf(m[12], cxp, fmaf(m[13], vp,  m[15]));
    float rdet = 1.0f / fmaf(d00, d11, -d01*d10);
    float p00 = fmaf(n00, d11, -n01*d10) * rdet;
    float p01 = fmaf(n01, d00, -n00*d01) * rdet;
    float p10 = fmaf(n10, d11, -n11*d10) * rdet;
    float p11 = fmaf(n11, d00, -n10*d01) * rdet;
    vx = p00; vp = p11; cxp = 0.5f*(p01 + p10);
}

// Block-shared LUT: threads 0-3 fill lutc[j] = ML^(sg*4+j) (16 floats) and
// lutf[j] = ((I+dtK)^32)^(sg*4+j) (4 floats).
__device__ __forceinline__ void build_lut(const M16& ml, const float* kp, int sg,
                                          int tid, float (*lutc)[16], float (*lutf)[4])
{
    if (tid < 4) {
        const int s = sg*4 + tid;
        float acc[16] = {1,0,0,0, 0,1,0,0, 0,0,1,0, 0,0,0,1};
        float bas[16];
        #pragma unroll
        for (int i = 0; i < 16; ++i) bas[i] = ml.m[i];
        #pragma unroll
        for (int it = 0; it < 6; ++it) {
            float t[16];
            if ((s >> it) & 1) {
                mat4_mul(acc, bas, t);
                #pragma unroll
                for (int i = 0; i < 16; ++i) acc[i] = t[i];
            }
            if (it < 5) {
                mat4_mul(bas, bas, t);
                #pragma unroll
                for (int i = 0; i < 16; ++i) bas[i] = t[i];
            }
        }
        #pragma unroll
        for (int i = 0; i < 16; ++i) lutc[tid][i] = acc[i];

        float m00 = fmaf(DT,kp[0],1.f), m01 = DT*kp[1];
        float m10 = DT*kp[2],           m11 = fmaf(DT,kp[3],1.f);
        #pragma unroll
        for (int i = 0; i < 5; ++i) {            // (I+dtK)^32
            float a = fmaf(m00,m00, m01*m10);
            float q = fmaf(m00,m01, m01*m11);
            float c = fmaf(m10,m00, m11*m10);
            float d = fmaf(m10,m01, m11*m11);
            m00=a; m01=q; m10=c; m11=d;
        }
        float a00=1.f, a01=0.f, a10=0.f, a11=1.f;
        #pragma unroll
        for (int it = 0; it < 6; ++it) {
            if ((s >> it) & 1) {
                float x0 = fmaf(a00,m00, a01*m10);
                float x1 = fmaf(a00,m01, a01*m11);
                float x2 = fmaf(a10,m00, a11*m10);
                float x3 = fmaf(a10,m01, a11*m11);
                a00=x0; a01=x1; a10=x2; a11=x3;
            }
            if (it < 5) {
                float x0 = fmaf(m00,m00, m01*m10);
                float x1 = fmaf(m00,m01, m01*m11);
                float x2 = fmaf(m10,m00, m11*m10);
                float x3 = fmaf(m10,m01, m11*m11);
                m00=x0; m01=x1; m10=x2; m11=x3;
            }
        }
        lutf[tid][0]=a00; lutf[tid][1]=a01; lutf[tid][2]=a10; lutf[tid][3]=a11;
    }
}

} // namespace gk

// ---------------------------------------------------------------- k1
__global__ void __launch_bounds__(256, 4)
k1_xq(const float* __restrict__ dy, const float* __restrict__ state,
      const float* __restrict__ fin, const float* __restrict__ kp,
      M16 mc, float* __restrict__ ws)
{
    using namespace gk;
    __shared__ float lutc[4][16];
    __shared__ float lutf[4][4];
    const int tid  = threadIdx.x;
    const int lane = tid & 63;
    const int wv   = tid >> 6;
    const int bg   = blockIdx.x, sg = blockIdx.y;   // grid (64,16)
    const int bidx = lane & 15,  sidx = lane >> 4;
    const int b    = bg*64 + wv*16 + bidx;
    const int s    = sg*4 + sidx;

    const float k00 = kp[0], k01 = kp[1], k10 = kp[2], k11 = kp[3];

    // Direct per-lane loads: 16 consecutive f4 = 256B contiguous.
    const float4* base = reinterpret_cast<const float4*>(dy)
                       + (size_t)b*ROWF4 + sg*64 + sidx*16;
    float4 v[16];
    #pragma unroll
    for (int j = 0; j < 16; ++j) v[j] = base[j];

    build_lut(mc, kp, sg, tid, lutc, lutf);

    float vx = state[b*6+2], vp = state[b*6+3], cxp = state[b*6+4];
    float f0 = fin[b*2+0],   f1 = fin[b*2+1];
    __syncthreads();

    // Checkpoint via LUT (broadcast reads within 16-lane groups).
    float m[16];
    #pragma unroll
    for (int i = 0; i < 16; ++i) m[i] = lutc[sidx][i];
    lft_apply(m, vx, vp, cxp);
    {
        float a00=lutf[sidx][0], a01=lutf[sidx][1];
        float a10=lutf[sidx][2], a11=lutf[sidx][3];
        float nf0 = fmaf(a00, f0, a01*f1);
        float nf1 = fmaf(a10, f0, a11*f1);
        f0 = nf0; f1 = nf1;
    }

    float X00 = 1.f, X01 = 0.f, X10 = 0.f, X11 = 1.f, Q0 = 0.f, Q1 = 0.f;

    #pragma unroll
    for (int j = 0; j < 16; ++j) {
        #pragma unroll
        for (int h = 0; h < 2; ++h) {
            float dy0 = h ? v[j].z : v[j].x;
            float xi0, xi1, nf0;
            covf_step(vx, vp, cxp, f0, f1, k00, k01, k10, k11, xi0, xi1, nf0);
            float p00 = fmaf(-DTC, xi0, P00c);
            float p10 = fmaf(-DTC, xi1, P10c);
            float r0  = xi0*dy0;
            float r1  = fmaf(DT, nf0, xi1*dy0);
            float nX00 = fmaf(p00, X00, P01c*X10);
            float nX01 = fmaf(p00, X01, P01c*X11);
            float nX10 = fmaf(p10, X00, P11c*X10);
            float nX11 = fmaf(p10, X01, P11c*X11);
            float nQ0  = fmaf(p00, Q0, fmaf(P01c, Q1, r0));
            float nQ1  = fmaf(p10, Q0, fmaf(P11c, Q1, r1));
            X00 = nX00; X01 = nX01; X10 = nX10; X11 = nX11; Q0 = nQ0; Q1 = nQ1;
        }
    }

    float* PQ = ws;
    const int sb = s*NBATCH + b;
    PQ[0*PLANE+sb] = X00;  PQ[1*PLANE+sb] = X01;
    PQ[2*PLANE+sb] = X10;  PQ[3*PLANE+sb] = X11;
    PQ[4*PLANE+sb] = Q0;   PQ[5*PLANE+sb] = Q1;
}

// ---------------------------------------------------------------- kfold
__global__ void __launch_bounds__(64, 1)
kfold(const float* __restrict__ state, float* __restrict__ ws)
{
    using namespace gk;
    constexpr int CH = 8, NC = NSEG / CH;
    const int b = blockIdx.x*64 + threadIdx.x;

    float* p0 = ws + 0*PLANE; float* p1 = ws + 1*PLANE;
    float* p2 = ws + 2*PLANE; float* p3 = ws + 3*PLANE;
    float* p4 = ws + 4*PLANE; float* p5 = ws + 5*PLANE;

    float x0 = state[b*6+0], x1 = state[b*6+1];

    float cur[CH*6], nxt[CH*6];
    #pragma unroll
    for (int j = 0; j < CH; ++j) {
        int idx = j*NBATCH + b;
        cur[j*6+0]=p0[idx]; cur[j*6+1]=p1[idx]; cur[j*6+2]=p2[idx];
        cur[j*6+3]=p3[idx]; cur[j*6+4]=p4[idx]; cur[j*6+5]=p5[idx];
    }
    #pragma unroll 1
    for (int ch = 0; ch < NC; ++ch) {
        if (ch < NC-1) {
            #pragma unroll
            for (int j = 0; j < CH; ++j) {
                int idx = ((ch+1)*CH + j)*NBATCH + b;
                nxt[j*6+0]=p0[idx]; nxt[j*6+1]=p1[idx]; nxt[j*6+2]=p2[idx];
                nxt[j*6+3]=p3[idx]; nxt[j*6+4]=p4[idx]; nxt[j*6+5]=p5[idx];
            }
        }
        #pragma unroll
        for (int j = 0; j < CH; ++j) {
            int idx = (ch*CH + j)*NBATCH + b;
            p4[idx] = x0; p5[idx] = x1;
            float nx0 = fmaf(cur[j*6+0], x0, fmaf(cur[j*6+1], x1, cur[j*6+4]));
            float nx1 = fmaf(cur[j*6+2], x0, fmaf(cur[j*6+3], x1, cur[j*6+5]));
            x0 = nx0; x1 = nx1;
        }
        #pragma unroll
        for (int i = 0; i < CH*6; ++i) cur[i] = nxt[i];
    }
}

// ---------------------------------------------------------------- k2
__global__ void __launch_bounds__(256, 4)
k2_replay(const float* __restrict__ dy, const float* __restrict__ state,
          const float* __restrict__ fin, const float* __restrict__ kp,
          M16 mc, const float* __restrict__ ws, float* __restrict__ out)
{
    using namespace gk;
    __shared__ float lutc[4][16];
    __shared__ float lutf[4][4];
    const int tid  = threadIdx.x;
    const int lane = tid & 63;
    const int wv   = tid >> 6;
    const int bg   = blockIdx.x, sg = blockIdx.y;
    const int bidx = lane & 15,  sidx = lane >> 4;
    const int b    = bg*64 + wv*16 + bidx;
    const int s    = sg*4 + sidx;
    const int sb   = s*NBATCH + b;

    const float k00 = kp[0], k01 = kp[1], k10 = kp[2], k11 = kp[3];

    const float4* base = reinterpret_cast<const float4*>(dy)
                       + (size_t)b*ROWF4 + sg*64 + sidx*16;
    float4 v[16];
    #pragma unroll
    for (int j = 0; j < 16; ++j) v[j] = base[j];

    build_lut(mc, kp, sg, tid, lutc, lutf);

    float vx = state[b*6+2], vp = state[b*6+3], cxp = state[b*6+4];
    float f0 = fin[b*2+0],   f1 = fin[b*2+1];
    float x0 = ws[4*PLANE + sb], x1 = ws[5*PLANE + sb];   // folded x_start
    __syncthreads();

    float m[16];
    #pragma unroll
    for (int i = 0; i < 16; ++i) m[i] = lutc[sidx][i];
    lft_apply(m, vx, vp, cxp);
    {
        float a00=lutf[sidx][0], a01=lutf[sidx][1];
        float a10=lutf[sidx][2], a11=lutf[sidx][3];
        float nf0 = fmaf(a00, f0, a01*f1);
        float nf1 = fmaf(a10, f0, a11*f1);
        f0 = nf0; f1 = nf1;
    }

    #pragma unroll
    for (int j = 0; j < 16; ++j) {
        float yh0, yh1;
        #pragma unroll
        for (int h = 0; h < 2; ++h) {
            float dy0 = h ? v[j].z : v[j].x;
            float yh  = YC * x0;              // pre-update x
            if (h) yh1 = yh; else yh0 = yh;
            float xi0, xi1, nf0;
            covf_step(vx, vp, cxp, f0, f1, k00, k01, k10, k11, xi0, xi1, nf0);
            float p00 = fmaf(-DTC, xi0, P00c);
            float p10 = fmaf(-DTC, xi1, P10c);
            float r0  = xi0*dy0;
            float r1  = fmaf(DT, nf0, xi1*dy0);
            float nx0 = fmaf(p00, x0, fmaf(P01c, x1, r0));
            float nx1 = fmaf(p10, x0, fmaf(P11c, x1, r1));
            x0 = nx0; x1 = nx1;
        }
        v[j] = make_float4(yh0, 0.f, yh1, 0.f);
    }

    // Direct per-lane stores: 256B contiguous.
    float4* dst = reinterpret_cast<float4*>(out + 6*NBATCH)
                + (size_t)b*ROWF4 + sg*64 + sidx*16;
    #pragma unroll
    for (int j = 0; j < 16; ++j) dst[j] = v[j];

    if (s == NSEG-1) {
        out[b*6+0] = x0; out[b*6+1] = x1;
        out[b*6+2] = vx; out[b*6+3] = vp; out[b*6+4] = cxp;
        out[b*6+5] = state[b*6+5] + 2.048f;
        float* fo = out + 6*NBATCH + (size_t)NBATCH*NT*2;
        fo[b*2+0] = f0; fo[b*2+1] = f1;
    }
}

// Host: LFT step matrix (Kalman form) ^ 32, in double.
static M16 build_m_pow(int log2l)
{
    const double dt = 0.001;
    const double a00 = -0.15, a01 = 6.283185, a10 = -6.283185, a11 = -0.15;
    const double qq = dt * 4.0 * 0.8 * 0.9;
    const double qd = dt * 5.25;
    const double h00 = 1.0 + dt*a00, h01 = dt*a01;
    const double h10 = dt*a10,       h11 = 1.0 + dt*a11;
    const double det = h00*h11 - h01*h10;
    const double t00 = h11/det, t01 = -h10/det, t10 = -h01/det, t11 = h00/det;
    const double g00 = t00*qq, g10 = t10*qq;
    double M[4][4] = {
        { h00 + qd*g00, h01, qd*t00, qd*t01 },
        { h10 + qd*g10, h11, qd*t10, qd*t11 },
        { g00,          0.0, t00,    t01    },
        { g10,          0.0, t10,    t11    },
    };
    for (int it = 0; it < log2l; ++it) {
        double R[4][4];
        for (int i = 0; i < 4; ++i)
            for (int j = 0; j < 4; ++j) {
                double acc = 0.0;
                for (int k = 0; k < 4; ++k) acc += M[i][k]*M[k][j];
                R[i][j] = acc;
            }
        for (int i = 0; i < 4; ++i)
            for (int j = 0; j < 4; ++j) M[i][j] = R[i][j];
    }
    M16 r;
    for (int i = 0; i < 4; ++i)
        for (int j = 0; j < 4; ++j) r.m[i*4+j] = (float)M[i][j];
    return r;
}

extern "C" void kernel_launch(void* const* d_in, const int* in_sizes, int n_in,
                              void* d_out, int out_size, void* d_ws, size_t ws_size,
                              hipStream_t stream)
{
    const float* dy    = (const float*)d_in[0];
    const float* state = (const float*)d_in[1];
    const float* fin   = (const float*)d_in[2];
    const float* kp    = (const float*)d_in[3];
    float* out = (float*)d_out;
    float* ws  = (float*)d_ws;   // 6 planes * 64*4096 * 4B = 6.29 MiB

    M16 mc = build_m_pow(5);     // ML = M_step^32

    dim3 grid(NBATCH/64, NSEG/4);   // (64, 16), 256-thread blocks
    k1_xq<<<grid, dim3(256), 0, stream>>>(dy, state, fin, kp, mc, ws);
    kfold<<<dim3(NBATCH/64), dim3(64), 0, stream>>>(state, ws);
    k2_replay<<<grid, dim3(256), 0, stream>>>(dy, state, fin, kp, mc, ws, out);
}

// Round 11
// 43.548 us; speedup vs baseline: 1.6813x; 1.6813x over previous
//
#include <hip/hip_runtime.h>
#include <cmath>

// GRNN_3547642986522 — B=4096 filters, T=2048 steps. SINGLE FUSED KERNEL.
// Math: cov (Riccati) evolves by a CONSTANT linear-fractional transform per
// step (Euler step == Kalman LFT step to O(dt^2)); host computes ML = M^32 in
// double. x is affine given cov; f linear; t closed-form.
// Mapping: wave = 1 batch, lane = 1 segment (64 segs x 32 steps).
//  - lane s: checkpoint cov/f at t=32s via per-lane binary matpow of ML;
//  - phase 1: accumulate segment transfer x_end = X x_start + Q (reads dy);
//  - wave-scan (6 shfl_up steps) composes the 64 affine maps -> exclusive
//    prefix -> x at each segment start (replaces kfold + ws round-trip);
//  - phase 2: replay 32 steps emitting dy_hat; lane 63 writes nstate/fnew.
// Memory: wave covers one contiguous 16KB row (loads+stores); block = 4
// consecutive rows (64KB), XCD-swizzled -> per-XCD streaming. dy read once,
// held in registers across both phases. No LDS, no workspace, one launch.

#define NBATCH 4096
#define NT     2048
#define ROWF4  1024        // float4 per dy row

struct M16 { float m[16]; };

namespace gk {

constexpr float DT   = 0.001f;
constexpr float A00  = -0.15f;
constexpr float A01  = 6.283185f;
constexpr float A10  = -6.283185f;
constexpr float A11  = -0.15f;
constexpr float C0   = 1.6970562748477141f;
constexpr float DD   = 5.25f;

constexpr float P00c = 1.0f + DT*A00;
constexpr float P01c = DT*A01;
constexpr float P10c = DT*A10;
constexpr float P11c = 1.0f + DT*A11;
constexpr float DTC  = DT*C0;
constexpr float QQ   = DT*C0*C0;
constexpr float cVA  = 1.0f + 2.0f*DT*A00;
constexpr float cVB  = 2.0f*DT*A01;
constexpr float cVBn = 2.0f*DT*A10;
constexpr float cVD  = DT*DD;
constexpr float cCA  = 1.0f + DT*(A00+A11);
constexpr float cCB  = DT*A10;
constexpr float cCC  = DT*A01;
constexpr float YC   = C0*DT;

__device__ __forceinline__ void cov_step(float& vx, float& vp, float& cxp)
{
    float a1 = fmaf(-QQ, vx,  cVA);
    float b1 = fmaf(cVB, cxp, cVD);
    float a2 = fmaf(-QQ, cxp, cVBn);
    float b2 = fmaf(a2,  cxp, cVD);
    float a3 = fmaf(-QQ, vx,  cCA);
    float m  = cCC * vp;
    float c3 = fmaf(cCB, vx,  m);
    float nvx = fmaf(a1,  vx,  b1);
    float nvp = fmaf(cVA, vp,  b2);
    float ncx = fmaf(a3,  cxp, c3);
    vx = nvx; vp = nvp; cxp = ncx;
}

__device__ __forceinline__ void covf_step(
    float& vx, float& vp, float& cxp, float& f0, float& f1,
    float k00, float k01, float k10, float k11,
    float& xi0o, float& xi1o, float& nf0o)
{
    float xi0 = C0*vx, xi1 = C0*cxp;
    float nf0 = fmaf(DT, fmaf(k00, f0, k01*f1), f0);
    float nf1 = fmaf(DT, fmaf(k10, f0, k11*f1), f1);
    xi0o = xi0; xi1o = xi1; nf0o = nf0;
    cov_step(vx, vp, cxp);
    f0 = nf0; f1 = nf1;
}

__device__ __forceinline__ void mat4_mul(const float* A, const float* B, float* C)
{
    #pragma unroll
    for (int i = 0; i < 4; ++i)
        #pragma unroll
        for (int j = 0; j < 4; ++j) {
            float acc = A[i*4+0] * B[0*4+j];
            acc = fmaf(A[i*4+1], B[1*4+j], acc);
            acc = fmaf(A[i*4+2], B[2*4+j], acc);
            acc = fmaf(A[i*4+3], B[3*4+j], acc);
            C[i*4+j] = acc;
        }
}

// P -> (E P + F)(G P + H)^-1, P = [[vx,cxp],[cxp,vp]].
__device__ __forceinline__ void lft_apply(const float* m, float& vx, float& vp, float& cxp)
{
    float n00 = fmaf(m[0], vx,  fmaf(m[1], cxp, m[2]));
    float n01 = fmaf(m[0], cxp, fmaf(m[1], vp,  m[3]));
    float n10 = fmaf(m[4], vx,  fmaf(m[5], cxp, m[6]));
    float n11 = fmaf(m[4], cxp, fmaf(m[5], vp,  m[7]));
    float d00 = fmaf(m[8],  vx,  fmaf(m[9],  cxp, m[10]));
    float d01 = fmaf(m[8],  cxp, fmaf(m[9],  vp,  m[11]));
    float d10 = fmaf(m[12], vx,  fmaf(m[13], cxp, m[14]));
    float d11 = fmaf(m[12], cxp, fmaf(m[13], vp,  m[15]));
    float rdet = 1.0f / fmaf(d00, d11, -d01*d10);
    float p00 = fmaf(n00, d11, -n01*d10) * rdet;
    float p01 = fmaf(n01, d00, -n00*d01) * rdet;
    float p10 = fmaf(n10, d11, -n11*d10) * rdet;
    float p11 = fmaf(n11, d00, -n10*d01) * rdet;
    vx = p00; vp = p11; cxp = 0.5f*(p01 + p10);
}

// Per-lane checkpoint at segment start s: cov via lft(ML^s), f via Mf32^s.
__device__ __forceinline__ void seg_checkpoint(
    const M16& ml, int s,
    float k00, float k01, float k10, float k11,
    float& vx, float& vp, float& cxp, float& f0, float& f1)
{
    float acc[16] = {1,0,0,0, 0,1,0,0, 0,0,1,0, 0,0,0,1};
    float bas[16];
    #pragma unroll
    for (int i = 0; i < 16; ++i) bas[i] = ml.m[i];
    #pragma unroll
    for (int it = 0; it < 6; ++it) {
        float t[16];
        if ((s >> it) & 1) {
            mat4_mul(acc, bas, t);
            #pragma unroll
            for (int i = 0; i < 16; ++i) acc[i] = t[i];
        }
        if (it < 5) {
            mat4_mul(bas, bas, t);
            #pragma unroll
            for (int i = 0; i < 16; ++i) bas[i] = t[i];
        }
    }
    lft_apply(acc, vx, vp, cxp);

    float m00 = fmaf(DT,k00,1.f), m01 = DT*k01;
    float m10 = DT*k10,           m11 = fmaf(DT,k11,1.f);
    #pragma unroll
    for (int i = 0; i < 5; ++i) {            // (I + dt K)^32
        float a = fmaf(m00,m00, m01*m10);
        float q = fmaf(m00,m01, m01*m11);
        float c = fmaf(m10,m00, m11*m10);
        float d = fmaf(m10,m01, m11*m11);
        m00=a; m01=q; m10=c; m11=d;
    }
    float a00=1.f, a01=0.f, a10=0.f, a11=1.f;
    #pragma unroll
    for (int it = 0; it < 6; ++it) {
        if ((s >> it) & 1) {
            float x0 = fmaf(a00,m00, a01*m10);
            float x1 = fmaf(a00,m01, a01*m11);
            float x2 = fmaf(a10,m00, a11*m10);
            float x3 = fmaf(a10,m01, a11*m11);
            a00=x0; a01=x1; a10=x2; a11=x3;
        }
        if (it < 5) {
            float x0 = fmaf(m00,m00, m01*m10);
            float x1 = fmaf(m00,m01, m01*m11);
            float x2 = fmaf(m10,m00, m11*m10);
            float x3 = fmaf(m10,m01, m11*m11);
            m00=x0; m01=x1; m10=x2; m11=x3;
        }
    }
    float nf0 = fmaf(a00, f0, a01*f1);
    float nf1 = fmaf(a10, f0, a11*f1);
    f0 = nf0; f1 = nf1;
}

// XCD-aware bijective swizzle (n % 8 == 0).
__device__ __forceinline__ int xcd_swz(int bx, int n)
{
    return (bx & 7) * (n >> 3) + (bx >> 3);
}

} // namespace gk

// ------------------------------------------------------------- fused kernel
__global__ void __launch_bounds__(256, 3)
kfused(const float* __restrict__ dy, const float* __restrict__ state,
       const float* __restrict__ fin, const float* __restrict__ kp,
       M16 mc, float* __restrict__ out)
{
    using namespace gk;
    const int lane = threadIdx.x & 63;
    const int wv   = threadIdx.x >> 6;
    const int g    = xcd_swz(blockIdx.x, gridDim.x);   // 1024 blocks
    const int b    = g*4 + wv;                         // wave-uniform batch
    const int s    = lane;                             // lane = segment

    // Wave-uniform small loads (scalarized by compiler).
    const float k00 = kp[0], k01 = kp[1], k10 = kp[2], k11 = kp[3];
    const float x0i = state[b*6+0], x1i = state[b*6+1];
    const float vx0 = state[b*6+2], vp0 = state[b*6+3], cx0 = state[b*6+4];
    const float t0  = state[b*6+5];
    const float f0i = fin[b*2+0],   f1i = fin[b*2+1];

    // Load the lane's 256B dy slice (wave covers one contiguous 16KB row).
    const float4* base = reinterpret_cast<const float4*>(dy)
                       + (size_t)b*ROWF4 + s*16;
    float4 v[16];
    #pragma unroll
    for (int j = 0; j < 16; ++j) v[j] = base[j];

    // Checkpoint cov/f at segment start (hidden under load flight).
    float vx = vx0, vp = vp0, cxp = cx0, f0 = f0i, f1 = f1i;
    seg_checkpoint(mc, s, k00, k01, k10, k11, vx, vp, cxp, f0, f1);
    const float vxs = vx, vps = vp, cxs = cxp, f0s = f0, f1s = f1;

    // ---- Phase 1: per-segment affine map x_end = X x_start + Q.
    float X00 = 1.f, X01 = 0.f, X10 = 0.f, X11 = 1.f, Q0 = 0.f, Q1 = 0.f;
    #pragma unroll
    for (int j = 0; j < 16; ++j) {
        #pragma unroll
        for (int h = 0; h < 2; ++h) {
            float dy0 = h ? v[j].z : v[j].x;
            float xi0, xi1, nf0;
            covf_step(vx, vp, cxp, f0, f1, k00, k01, k10, k11, xi0, xi1, nf0);
            float p00 = fmaf(-DTC, xi0, P00c);
            float p10 = fmaf(-DTC, xi1, P10c);
            float r0  = xi0*dy0;
            float r1  = fmaf(DT, nf0, xi1*dy0);
            float nX00 = fmaf(p00, X00, P01c*X10);
            float nX01 = fmaf(p00, X01, P01c*X11);
            float nX10 = fmaf(p10, X00, P11c*X10);
            float nX11 = fmaf(p10, X01, P11c*X11);
            float nQ0  = fmaf(p00, Q0, fmaf(P01c, Q1, r0));
            float nQ1  = fmaf(p10, Q0, fmaf(P11c, Q1, r1));
            X00 = nX00; X01 = nX01; X10 = nX10; X11 = nX11; Q0 = nQ0; Q1 = nQ1;
        }
    }

    // ---- Wave-scan: inclusive prefix composition of the 64 affine maps.
    // compose(own, recv): apply recv first, then own.
    float A00 = X00, A01 = X01, A10 = X10, A11 = X11, B0 = Q0, B1 = Q1;
    #pragma unroll
    for (int d = 1; d < 64; d <<= 1) {
        float r00 = __shfl_up(A00, d);
        float r01 = __shfl_up(A01, d);
        float r10 = __shfl_up(A10, d);
        float r11 = __shfl_up(A11, d);
        float rB0 = __shfl_up(B0,  d);
        float rB1 = __shfl_up(B1,  d);
        if (lane >= d) {
            float n00 = fmaf(A00, r00, A01*r10);
            float n01 = fmaf(A00, r01, A01*r11);
            float n10 = fmaf(A10, r00, A11*r10);
            float n11 = fmaf(A10, r01, A11*r11);
            float nB0 = fmaf(A00, rB0, fmaf(A01, rB1, B0));
            float nB1 = fmaf(A10, rB0, fmaf(A11, rB1, B1));
            A00=n00; A01=n01; A10=n10; A11=n11; B0=nB0; B1=nB1;
        }
    }
    // Exclusive prefix -> x at this segment's start.
    float e00 = __shfl_up(A00, 1);
    float e01 = __shfl_up(A01, 1);
    float e10 = __shfl_up(A10, 1);
    float e11 = __shfl_up(A11, 1);
    float eB0 = __shfl_up(B0,  1);
    float eB1 = __shfl_up(B1,  1);
    float x0 = (s == 0) ? x0i : fmaf(e00, x0i, fmaf(e01, x1i, eB0));
    float x1 = (s == 0) ? x1i : fmaf(e10, x0i, fmaf(e11, x1i, eB1));

    // ---- Phase 2: replay from checkpoint, emit dy_hat into v[].
    vx = vxs; vp = vps; cxp = cxs; f0 = f0s; f1 = f1s;
    #pragma unroll
    for (int j = 0; j < 16; ++j) {
        float yh0, yh1;
        #pragma unroll
        for (int h = 0; h < 2; ++h) {
            float dy0 = h ? v[j].z : v[j].x;
            float yh  = YC * x0;              // dy_hat uses pre-update x
            if (h) yh1 = yh; else yh0 = yh;
            float xi0, xi1, nf0;
            covf_step(vx, vp, cxp, f0, f1, k00, k01, k10, k11, xi0, xi1, nf0);
            float p00 = fmaf(-DTC, xi0, P00c);
            float p10 = fmaf(-DTC, xi1, P10c);
            float r0  = xi0*dy0;
            float r1  = fmaf(DT, nf0, xi1*dy0);
            float nx0 = fmaf(p00, x0, fmaf(P01c, x1, r0));
            float nx1 = fmaf(p10, x0, fmaf(P11c, x1, r1));
            x0 = nx0; x1 = nx1;
        }
        v[j] = make_float4(yh0, 0.f, yh1, 0.f);
    }

    // Store the lane's 256B dy_hat slice (wave covers contiguous 16KB row).
    float4* dst = reinterpret_cast<float4*>(out + 6*NBATCH)
                + (size_t)b*ROWF4 + s*16;
    #pragma unroll
    for (int j = 0; j < 16; ++j) dst[j] = v[j];

    // Lane 63 finished t=2048: write nstate and fnew.
    if (s == 63) {
        out[b*6+0] = x0; out[b*6+1] = x1;
        out[b*6+2] = vx; out[b*6+3] = vp; out[b*6+4] = cxp;
        out[b*6+5] = t0 + 2.048f;
        float* fo = out + 6*NBATCH + (size_t)NBATCH*NT*2;
        fo[b*2+0] = f0; fo[b*2+1] = f1;
    }
}

// Host: LFT step matrix (Kalman form) ^ 32, computed in double.
static M16 build_m_pow(int log2l)
{
    const double dt = 0.001;
    const double a00 = -0.15, a01 = 6.283185, a10 = -6.283185, a11 = -0.15;
    const double qq = dt * 4.0 * 0.8 * 0.9;
    const double qd = dt * 5.25;
    const double h00 = 1.0 + dt*a00, h01 = dt*a01;
    const double h10 = dt*a10,       h11 = 1.0 + dt*a11;
    const double det = h00*h11 - h01*h10;
    const double t00 = h11/det, t01 = -h10/det, t10 = -h01/det, t11 = h00/det;
    const double g00 = t00*qq, g10 = t10*qq;
    double M[4][4] = {
        { h00 + qd*g00, h01, qd*t00, qd*t01 },
        { h10 + qd*g10, h11, qd*t10, qd*t11 },
        { g00,          0.0, t00,    t01    },
        { g10,          0.0, t10,    t11    },
    };
    for (int it = 0; it < log2l; ++it) {
        double R[4][4];
        for (int i = 0; i < 4; ++i)
            for (int j = 0; j < 4; ++j) {
                double acc = 0.0;
                for (int k = 0; k < 4; ++k) acc += M[i][k]*M[k][j];
                R[i][j] = acc;
            }
        for (int i = 0; i < 4; ++i)
            for (int j = 0; j < 4; ++j) M[i][j] = R[i][j];
    }
    M16 r;
    for (int i = 0; i < 4; ++i)
        for (int j = 0; j < 4; ++j) r.m[i*4+j] = (float)M[i][j];
    return r;
}

extern "C" void kernel_launch(void* const* d_in, const int* in_sizes, int n_in,
                              void* d_out, int out_size, void* d_ws, size_t ws_size,
                              hipStream_t stream)
{
    const float* dy    = (const float*)d_in[0];
    const float* state = (const float*)d_in[1];
    const float* fin   = (const float*)d_in[2];
    const float* kp    = (const float*)d_in[3];
    float* out = (float*)d_out;

    M16 mc = build_m_pow(5);     // ML = M_step^32

    kfused<<<dim3(NBATCH/4), dim3(256), 0, stream>>>(dy, state, fin, kp, mc, out);
}